// Round 5
// baseline (1077.608 us; speedup 1.0000x reference)
//
#include <hip/hip_runtime.h>
#include <stdint.h>

#define DD 1024
#define SS 2048
#define HH 16
#define HDD 64
#define NTOK 8192

typedef unsigned short u16;
typedef __attribute__((ext_vector_type(8))) short bf16x8;
typedef __attribute__((ext_vector_type(4))) float f32x4;
typedef __attribute__((ext_vector_type(4))) u16 u16x4;
typedef __attribute__((address_space(1))) unsigned int u32a1;
typedef __attribute__((address_space(3))) unsigned int u32a3;

__device__ __forceinline__ float bf2f(u16 u){
  union { float f; unsigned v; } c; c.v = ((unsigned)u) << 16; return c.f;
}
__device__ __forceinline__ u16 f2bf(float f){
  unsigned x = __float_as_uint(f);
  x = (x + 0x7fffu + ((x >> 16) & 1u)) >> 16;
  return (u16)x;
}
__device__ __forceinline__ void async16(const u16* g, u16* l){
  __builtin_amdgcn_global_load_lds((const u32a1*)g, (u32a3*)l, 16, 0, 0);
}
// unified LDS swizzle for stride-64(u16) rows: conflict-free for both
// column-scatter writes (row varies in high bits) and row-fragment b128
// reads (row varies in low bits). Verified by bank enumeration.
__device__ __forceinline__ int vswz(int row){
  return (((row & 7) ^ ((row >> 3) & 7)) << 4);
}
// pack two f32 -> one u32 of 2 bf16 (RNE), src0 -> low half
__device__ __forceinline__ unsigned cvtpk(float lo, float hi){
  unsigned r;
  asm("v_cvt_pk_bf16_f32 %0, %1, %2" : "=v"(r) : "v"(lo), "v"(hi));
  return r;
}

// ---------------- elementwise kernels ----------------

__global__ __launch_bounds__(256) void f32_to_bf16_kernel(
    const float* __restrict__ in, u16* __restrict__ out, int n)
{
  int i = (blockIdx.x * 256 + threadIdx.x) * 4;
  if (i >= n) return;
  float4 v = *(const float4*)(in + i);
  u16x4 o; o.x = f2bf(v.x); o.y = f2bf(v.y); o.z = f2bf(v.z); o.w = f2bf(v.w);
  *(u16x4*)(out + i) = o;
}

// per-row RMSNorm; block max -> partials[row] (NO global atomics)
__global__ __launch_bounds__(256) void rmsnorm_absmax_kernel(
    const float* __restrict__ xin, const float* __restrict__ wgt,
    u16* __restrict__ nxo, float* __restrict__ pmax)
{
  const int row = blockIdx.x, t = threadIdx.x;
  const int w = t >> 6, l = t & 63;
  float4 xv = *(const float4*)(xin + (size_t)row * DD + t * 4);
  float ss = xv.x*xv.x + xv.y*xv.y + xv.z*xv.z + xv.w*xv.w;
  #pragma unroll
  for (int m = 1; m < 64; m <<= 1) ss += __shfl_xor(ss, m, 64);
  __shared__ float red[4];
  __shared__ float redm[4];
  if (l == 0) red[w] = ss;
  __syncthreads();
  float tot = red[0] + red[1] + red[2] + red[3];
  float rstd = rsqrtf(tot * (1.f / DD) + 1e-6f);
  float4 wv = *(const float4*)(wgt + t * 4);
  float o0 = xv.x * rstd * wv.x;
  float o1 = xv.y * rstd * wv.y;
  float o2 = xv.z * rstd * wv.z;
  float o3 = xv.w * rstd * wv.w;
  u16x4 ov; ov.x = f2bf(o0); ov.y = f2bf(o1); ov.z = f2bf(o2); ov.w = f2bf(o3);
  *(u16x4*)(nxo + (size_t)row * DD + t * 4) = ov;
  float lm = fmaxf(fmaxf(fabsf(o0), fabsf(o1)), fmaxf(fabsf(o2), fabsf(o3)));
  #pragma unroll
  for (int m = 1; m < 64; m <<= 1) lm = fmaxf(lm, __shfl_xor(lm, m, 64));
  if (l == 0) redm[w] = lm;
  __syncthreads();
  if (t == 0)
    pmax[row] = fmaxf(fmaxf(redm[0], redm[1]), fmaxf(redm[2], redm[3]));
}

// single-block fold of partial maxima -> amax scalar
__global__ __launch_bounds__(1024) void amax_reduce_kernel(
    const float* __restrict__ p, int n, unsigned* __restrict__ amax)
{
  const int t = threadIdx.x;
  float m = 0.f;
  for (int i = t; i < n; i += 1024) m = fmaxf(m, p[i]);
  #pragma unroll
  for (int msk = 1; msk < 64; msk <<= 1) m = fmaxf(m, __shfl_xor(m, msk, 64));
  __shared__ float red[16];
  if ((t & 63) == 0) red[t >> 6] = m;
  __syncthreads();
  if (t == 0){
    float mm = red[0];
    #pragma unroll
    for (int i = 1; i < 16; i++) mm = fmaxf(mm, red[i]);
    *amax = __float_as_uint(mm);
  }
}

__global__ __launch_bounds__(256) void quantize_kernel(
    const u16* __restrict__ in, u16* __restrict__ outq,
    const unsigned* __restrict__ amax, int n)
{
  int i = (blockIdx.x * 256 + threadIdx.x) * 8;
  if (i >= n) return;
  float am = __uint_as_float(*amax);
  float scale = am / 127.f + 1e-8f;
  float inv = 1.f / scale;
  uint4 a = *(const uint4*)(in + i);
  u16* u = (u16*)&a;
  #pragma unroll
  for (int j = 0; j < 8; j++){
    float v = bf2f(u[j]);
    float q = rintf(v * inv);            // RNE = jnp.round
    q = fminf(127.f, fmaxf(-128.f, q));
    u[j] = f2bf(q * scale);
  }
  *(uint4*)(outq + i) = a;
}

// ---------------- GEMM: C[M,N] = A[M,K](bf16) @ W[N,K]^T + bias, fused epilogues ----------------
// MODE 0: bf16 store            (out=u16*)
// MODE 1: recurrence: tanh(C+b + exp(decay[col])*h_prev) -> f32  (e0=decay, e1=h_prev)
// MODE 2: mid-residual: x + h_rec + (C+b) + depthwise_conv(nx) -> f32
//         (e0=x, e1=h_rec, e2=conv_w, e3=conv_b, eb0=nx)
// MODE 3: swiglu gate: silu(h1)*(C+b) -> bf16, block max -> pmax[block] (no atomics)
// MODE 4: out[idx] += (C+b)  (final residual)
template<int MODE>
__global__ __launch_bounds__(256) void gemm_bt(
    const u16* __restrict__ A, const u16* __restrict__ Wt,
    const float* __restrict__ bias, int M, int N, int K,
    void* __restrict__ out,
    const float* __restrict__ e0, const float* __restrict__ e1,
    const float* __restrict__ e2, const float* __restrict__ e3,
    const u16* __restrict__ eb0, float* __restrict__ pmax)
{
  __shared__ __align__(16) u16 Ash[128 * 32];
  __shared__ __align__(16) u16 Bsh[128 * 32];
  const int t = threadIdx.x, w = t >> 6, l = t & 63;
  const int brow = blockIdx.y * 128, bcol = blockIdx.x * 128;
  const int wr = w >> 1, wc = w & 1;
  f32x4 acc[4][4] = {};

  const u16* Ab = A + (size_t)brow * K;
  const u16* Bb = Wt + (size_t)bcol * K;
  const int r4 = t >> 2, c8 = (t & 3) * 8;

  for (int k0 = 0; k0 < K; k0 += 32){
    #pragma unroll
    for (int j = 0; j < 2; j++){
      async16(Ab + (size_t)(j * 64 + r4) * K + k0 + c8, &Ash[(j * 64 + r4) * 32 + c8]);
      async16(Bb + (size_t)(j * 64 + r4) * K + k0 + c8, &Bsh[(j * 64 + r4) * 32 + c8]);
    }
    __syncthreads();   // drains vmcnt(0): staged data visible
    bf16x8 af[4], bfr[4];
    #pragma unroll
    for (int m = 0; m < 4; m++)
      af[m] = *(const bf16x8*)&Ash[(wr * 64 + m * 16 + (l & 15)) * 32 + (l >> 4) * 8];
    #pragma unroll
    for (int n = 0; n < 4; n++)
      bfr[n] = *(const bf16x8*)&Bsh[(wc * 64 + n * 16 + (l & 15)) * 32 + (l >> 4) * 8];
    #pragma unroll
    for (int m = 0; m < 4; m++)
      #pragma unroll
      for (int n = 0; n < 4; n++)
        acc[m][n] = __builtin_amdgcn_mfma_f32_16x16x32_bf16(af[m], bfr[n], acc[m][n], 0, 0, 0);
    __syncthreads();   // all waves done reading before next stage
  }

  float localmax = 0.f;
  #pragma unroll
  for (int m = 0; m < 4; m++){
    #pragma unroll
    for (int n = 0; n < 4; n++){
      #pragma unroll
      for (int r = 0; r < 4; r++){
        const int row = brow + wr * 64 + m * 16 + (l >> 4) * 4 + r;
        const int col = bcol + wc * 64 + n * 16 + (l & 15);
        const size_t idx = (size_t)row * N + col;
        float v = acc[m][n][r] + bias[col];
        if constexpr (MODE == 0){
          ((u16*)out)[idx] = f2bf(v);
        } else if constexpr (MODE == 1){
          v = tanhf(v + expf(e0[col]) * e1[idx]);
          ((float*)out)[idx] = v;
        } else if constexpr (MODE == 2){
          const int s = row & (SS - 1);
          float hc = e3[col];
          const u16* np = eb0 + idx;
          #pragma unroll
          for (int j = 0; j < 5; j++){
            int sn = s + j - 2;
            if (sn >= 0 && sn < SS) hc += bf2f(np[(j - 2) * DD]) * e2[col * 5 + j];
          }
          ((float*)out)[idx] = v + e0[idx] + e1[idx] + hc;
        } else if constexpr (MODE == 3){
          float h1v = bf2f(eb0[idx]);
          float g = h1v / (1.f + expf(-h1v)) * v;   // silu(h1)*h2
          ((u16*)out)[idx] = f2bf(g);
          localmax = fmaxf(localmax, fabsf(g));
        } else {
          ((float*)out)[idx] += v;
        }
      }
    }
  }
  if constexpr (MODE == 3){
    #pragma unroll
    for (int msk = 1; msk < 64; msk <<= 1)
      localmax = fmaxf(localmax, __shfl_xor(localmax, msk, 64));
    __shared__ float wmax[4];
    if (l == 0) wmax[w] = localmax;
    __syncthreads();
    if (t == 0)
      pmax[blockIdx.y * gridDim.x + blockIdx.x] =
          fmaxf(fmaxf(wmax[0], wmax[1]), fmaxf(wmax[2], wmax[3]));
  }
}

// ---------------- flash attention v3: swapped QK^T, in-register softmax+P ----------------
// mfma(K,Q) puts P^T in C-layout: lane holds 16 P values for q=lane&15,
// kv = n*16 + (lane>>4)*4 + r. Softmax = in-lane reduce + 2 shfl_xor.
// P->PV A-fragment via cvt_pk_bf16 + 8 shfl/qt/kk (derivation in journal):
//   word w4 of A-frag (kv = kk*32+lh*8+2*w4,+1) = pk[2kk+(lh>>1)][w4&1]
//   from lane lm + 16*(2*(lh&1)+(w4>>1)).
__global__ __launch_bounds__(256) void attn_kernel(
    const u16* __restrict__ qkv, u16* __restrict__ attn_out)
{
  const int qb = blockIdx.x;        // 0..15 (128 q rows each)
  const int bh = blockIdx.y;        // 0..63
  const int h = bh & (HH - 1), b = bh >> 4;
  const int t = threadIdx.x, w = t >> 6, l = t & 63;
  const int lm = l & 15, lh = l >> 4;
  const int tok0 = b * SS;
  const size_t rstr = 3 * DD;

  __shared__ __align__(16) u16 Ksh[64 * 64];       // [key][hd], row-XOR swizzle
  __shared__ __align__(16) u16 Vsh[64 * 64];       // [hd][key], vswz swizzle

  const int qr0 = qb * 128 + w * 32;
  bf16x8 qf[2][2];
  #pragma unroll
  for (int qt = 0; qt < 2; qt++){
    const u16* qp = qkv + (size_t)(tok0 + qr0 + qt * 16 + lm) * rstr + h * HDD + lh * 8;
    qf[qt][0] = *(const bf16x8*)qp;
    qf[qt][1] = *(const bf16x8*)(qp + 32);
  }
  f32x4 acc_o[2][4] = {};
  float mrun[2] = {-1e30f, -1e30f};
  float lrun[2] = {0.f, 0.f};

  for (int kv0 = 0; kv0 < SS; kv0 += 64){
    // stage K (vectorized, row-swizzled) + V^T (scalar scatter, vswz)
    #pragma unroll
    for (int j = 0; j < 2; j++){
      const int krl = j * 32 + (t >> 3);
      const int c8 = (t & 7) * 8;
      const size_t rowb = (size_t)(tok0 + kv0 + krl) * rstr + h * HDD + c8;
      uint4 kv4 = *(const uint4*)(qkv + rowb + DD);
      *(uint4*)((char*)Ksh + (((krl * 64 + c8) * 2) ^ ((krl & 7) << 4))) = kv4;
      uint4 vv4 = *(const uint4*)(qkv + rowb + 2 * DD);
      const u16* vs = (const u16*)&vv4;
      #pragma unroll
      for (int i = 0; i < 8; i++){
        const int vr = c8 + i;
        *(u16*)((char*)Vsh + (((vr * 64 + krl) * 2) ^ vswz(vr))) = vs[i];
      }
    }
    __syncthreads();

    unsigned pk[2][4][2];
    #pragma unroll
    for (int qt = 0; qt < 2; qt++){
      // P^T = K @ Q^T (C-layout: lane = q-col lm, rows = kv)
      f32x4 sc[4];
      #pragma unroll
      for (int n = 0; n < 4; n++){
        f32x4 z = {};
        #pragma unroll
        for (int kk = 0; kk < 2; kk++){
          const int krow = n * 16 + lm;
          bf16x8 kf = *(const bf16x8*)((const char*)Ksh +
              (((krow * 64 + kk * 32 + lh * 8) * 2) ^ ((krow & 7) << 4)));
          z = __builtin_amdgcn_mfma_f32_16x16x32_bf16(kf, qf[qt][kk], z, 0, 0, 0);
        }
        sc[n] = z;
      }
      // online softmax, all in-lane for q=lm (scale 0.125 folded into exp arg)
      float m0 = sc[0][0];
      #pragma unroll
      for (int n = 0; n < 4; n++)
        #pragma unroll
        for (int r = 0; r < 4; r++) m0 = fmaxf(m0, sc[n][r]);
      m0 = fmaxf(m0, __shfl_xor(m0, 16, 64));
      m0 = fmaxf(m0, __shfl_xor(m0, 32, 64));
      m0 *= 0.125f;
      float mn = fmaxf(mrun[qt], m0);
      float al = __expf(mrun[qt] - mn);
      mrun[qt] = mn;
      lrun[qt] *= al;
      #pragma unroll
      for (int r = 0; r < 4; r++){
        float alr = __shfl(al, lh * 4 + r, 64);   // alpha for acc row q=lh*4+r
        #pragma unroll
        for (int n = 0; n < 4; n++) acc_o[qt][n][r] *= alr;
      }
      float rs = 0.f;
      #pragma unroll
      for (int n = 0; n < 4; n++)
        #pragma unroll
        for (int r = 0; r < 4; r++){
          float p = __expf(fmaf(sc[n][r], 0.125f, -mn));
          sc[n][r] = p;
          rs += p;
        }
      rs += __shfl_xor(rs, 16, 64);
      rs += __shfl_xor(rs, 32, 64);
      lrun[qt] += rs;
      #pragma unroll
      for (int n = 0; n < 4; n++){
        pk[qt][n][0] = cvtpk(sc[n][0], sc[n][1]);
        pk[qt][n][1] = cvtpk(sc[n][2], sc[n][3]);
      }
    }

    // O += P @ V : rebuild A-frag by lane redistribution, V shared by both qt
    #pragma unroll
    for (int kk = 0; kk < 2; kk++){
      bf16x8 pA[2];
      #pragma unroll
      for (int qt = 0; qt < 2; qt++){
        union { bf16x8 v; unsigned u[4]; } pa;
        #pragma unroll
        for (int w4 = 0; w4 < 4; w4++){
          const int src = lm + 16 * (2 * (lh & 1) + (w4 >> 1));
          unsigned a0 = (unsigned)__shfl((int)pk[qt][2 * kk + 0][w4 & 1], src, 64);
          unsigned a1 = (unsigned)__shfl((int)pk[qt][2 * kk + 1][w4 & 1], src, 64);
          pa.u[w4] = (lh >> 1) ? a1 : a0;
        }
        pA[qt] = pa.v;
      }
      #pragma unroll
      for (int n = 0; n < 4; n++){
        const int vr = n * 16 + lm;
        bf16x8 vf = *(const bf16x8*)((const char*)Vsh +
            (((vr * 64 + kk * 32 + lh * 8) * 2) ^ vswz(vr)));
        acc_o[0][n] = __builtin_amdgcn_mfma_f32_16x16x32_bf16(pA[0], vf, acc_o[0][n], 0, 0, 0);
        acc_o[1][n] = __builtin_amdgcn_mfma_f32_16x16x32_bf16(pA[1], vf, acc_o[1][n], 0, 0, 0);
      }
    }
    __syncthreads();
  }

  #pragma unroll
  for (int qt = 0; qt < 2; qt++){
    const float inv = 1.f / lrun[qt];
    #pragma unroll
    for (int r = 0; r < 4; r++){
      const float invr = __shfl(inv, lh * 4 + r, 64);
      const int row = tok0 + qr0 + qt * 16 + lh * 4 + r;
      #pragma unroll
      for (int n = 0; n < 4; n++)
        attn_out[(size_t)row * DD + h * HDD + n * 16 + lm] = f2bf(acc_o[qt][n][r] * invr);
    }
  }
}

// ---------------- host ----------------

extern "C" void kernel_launch(void* const* d_in, const int* in_sizes, int n_in,
                              void* d_out, int out_size, void* d_ws, size_t ws_size,
                              hipStream_t stream)
{
  (void)in_sizes; (void)n_in; (void)out_size; (void)ws_size;
  const float* x       = (const float*)d_in[0];
  const float* h_prev  = (const float*)d_in[1];
  const float* norm1_w = (const float*)d_in[2];
  const float* norm2_w = (const float*)d_in[3];
  const float* decay   = (const float*)d_in[4];
  const float* rec_W   = (const float*)d_in[5];
  const float* rec_b   = (const float*)d_in[6];
  const float* inp_W   = (const float*)d_in[7];
  const float* inp_b   = (const float*)d_in[8];
  const float* out_W   = (const float*)d_in[9];
  const float* out_b   = (const float*)d_in[10];
  const float* conv_w  = (const float*)d_in[11];
  const float* conv_b  = (const float*)d_in[12];
  const float* w1_W    = (const float*)d_in[13];
  const float* w1_b    = (const float*)d_in[14];
  const float* w2_W    = (const float*)d_in[15];
  const float* w2_b    = (const float*)d_in[16];
  const float* w3_W    = (const float*)d_in[17];
  const float* w3_b    = (const float*)d_in[18];

  const size_t NDe = (size_t)NTOK * DD;
  float* out_x = (float*)d_out;
  float* out_h = (float*)d_out + NDe;

  char* ws = (char*)d_ws;
  unsigned* amax1 = (unsigned*)ws;
  unsigned* amax2 = amax1 + 1;
  unsigned* amax3 = amax1 + 2;
  size_t off = 256;
  u16* Wrec = (u16*)(ws + off); off += (size_t)DD * DD * 2;
  u16* Winp = (u16*)(ws + off); off += (size_t)3 * DD * DD * 2;
  u16* Wout = (u16*)(ws + off); off += (size_t)DD * DD * 2;
  u16* W1   = (u16*)(ws + off); off += (size_t)4 * DD * DD * 2;
  u16* W2   = (u16*)(ws + off); off += (size_t)4 * DD * DD * 2;
  u16* W3   = (u16*)(ws + off); off += (size_t)4 * DD * DD * 2;
  u16* nx   = (u16*)(ws + off); off += NDe * 2;
  u16* xq   = (u16*)(ws + off); off += NDe * 2;
  u16* big  = (u16*)(ws + off); off += (size_t)NTOK * 4096 * 2;  // qkv+attn_out OR h1/g
  float* pmax1 = (float*)(ws + off); off += NTOK * 4;
  float* pmax2 = (float*)(ws + off); off += NTOK * 4;
  float* pmax3 = (float*)(ws + off); off += 2048 * 4;
  u16* qkvp    = big;
  u16* attnout = big + (size_t)NTOK * 3 * DD;

  // weights -> bf16
  f32_to_bf16_kernel<<<dim3(1024),  dim3(256), 0, stream>>>(rec_W, Wrec, DD * DD);
  f32_to_bf16_kernel<<<dim3(3072),  dim3(256), 0, stream>>>(inp_W, Winp, 3 * DD * DD);
  f32_to_bf16_kernel<<<dim3(1024),  dim3(256), 0, stream>>>(out_W, Wout, DD * DD);
  f32_to_bf16_kernel<<<dim3(4096),  dim3(256), 0, stream>>>(w1_W, W1, 4 * DD * DD);
  f32_to_bf16_kernel<<<dim3(4096),  dim3(256), 0, stream>>>(w2_W, W2, 4 * DD * DD);
  f32_to_bf16_kernel<<<dim3(4096),  dim3(256), 0, stream>>>(w3_W, W3, 4 * DD * DD);

  // phase 1: norm + absmax (two-stage, no atomics), quantize
  rmsnorm_absmax_kernel<<<dim3(NTOK), dim3(256), 0, stream>>>(x, norm1_w, nx, pmax1);
  amax_reduce_kernel<<<dim3(1), dim3(1024), 0, stream>>>(pmax1, NTOK, amax1);
  quantize_kernel<<<dim3(4096), dim3(256), 0, stream>>>(nx, xq, amax1, (int)NDe);

  // recurrence branch: h_rec -> out_h
  gemm_bt<1><<<dim3(8, 64), dim3(256), 0, stream>>>(xq, Wrec, rec_b, NTOK, DD, DD,
      out_h, decay, h_prev, nullptr, nullptr, nullptr, nullptr);
  // attention branch
  gemm_bt<0><<<dim3(24, 64), dim3(256), 0, stream>>>(nx, Winp, inp_b, NTOK, 3 * DD, DD,
      qkvp, nullptr, nullptr, nullptr, nullptr, nullptr, nullptr);
  attn_kernel<<<dim3(16, 64), dim3(256), 0, stream>>>(qkvp, attnout);
  // out-proj + residual + conv -> out_x (= x_mid)
  gemm_bt<2><<<dim3(8, 64), dim3(256), 0, stream>>>(attnout, Wout, out_b, NTOK, DD, DD,
      out_x, x, out_h, conv_w, conv_b, nx, nullptr);

  // phase 2: FFN
  rmsnorm_absmax_kernel<<<dim3(NTOK), dim3(256), 0, stream>>>(out_x, norm2_w, nx, pmax2);
  amax_reduce_kernel<<<dim3(1), dim3(1024), 0, stream>>>(pmax2, NTOK, amax2);
  quantize_kernel<<<dim3(4096), dim3(256), 0, stream>>>(nx, xq, amax2, (int)NDe);
  gemm_bt<0><<<dim3(32, 64), dim3(256), 0, stream>>>(xq, W1, w1_b, NTOK, 4 * DD, DD,
      big, nullptr, nullptr, nullptr, nullptr, nullptr, nullptr);
  gemm_bt<3><<<dim3(32, 64), dim3(256), 0, stream>>>(xq, W2, w2_b, NTOK, 4 * DD, DD,
      big, nullptr, nullptr, nullptr, nullptr, big, pmax3);
  amax_reduce_kernel<<<dim3(1), dim3(1024), 0, stream>>>(pmax3, 2048, amax3);
  quantize_kernel<<<dim3(16384), dim3(256), 0, stream>>>(big, big, amax3, NTOK * 4096);
  gemm_bt<4><<<dim3(8, 64), dim3(256), 0, stream>>>(big, W3, w3_b, NTOK, DD, 4 * DD,
      out_x, nullptr, nullptr, nullptr, nullptr, nullptr, nullptr);
}

// Round 6
// 1009.215 us; speedup vs baseline: 1.0678x; 1.0678x over previous
//
#include <hip/hip_runtime.h>
#include <stdint.h>

#define DD 1024
#define SS 2048
#define HH 16
#define HDD 64
#define NTOK 8192

typedef unsigned short u16;
typedef __attribute__((ext_vector_type(8))) short bf16x8;
typedef __attribute__((ext_vector_type(4))) float f32x4;
typedef __attribute__((ext_vector_type(4))) u16 u16x4;
typedef __attribute__((address_space(1))) unsigned int u32a1;
typedef __attribute__((address_space(3))) unsigned int u32a3;

__device__ __forceinline__ float bf2f(u16 u){
  union { float f; unsigned v; } c; c.v = ((unsigned)u) << 16; return c.f;
}
__device__ __forceinline__ u16 f2bf(float f){
  unsigned x = __float_as_uint(f);
  x = (x + 0x7fffu + ((x >> 16) & 1u)) >> 16;
  return (u16)x;
}
__device__ __forceinline__ void async16(const u16* g, u16* l){
  __builtin_amdgcn_global_load_lds((const u32a1*)g, (u32a3*)l, 16, 0, 0);
}
// unified LDS swizzle for stride-64(u16) rows (see round-4 derivation)
__device__ __forceinline__ int vswz(int row){
  return (((row & 7) ^ ((row >> 3) & 7)) << 4);
}
// pack two f32 -> one u32 of 2 bf16 (RNE), src0 -> low half
__device__ __forceinline__ unsigned cvtpk(float lo, float hi){
  unsigned r;
  asm("v_cvt_pk_bf16_f32 %0, %1, %2" : "=v"(r) : "v"(lo), "v"(hi));
  return r;
}

// ---------------- elementwise kernels ----------------

__global__ __launch_bounds__(256) void f32_to_bf16_kernel(
    const float* __restrict__ in, u16* __restrict__ out, int n)
{
  int i = (blockIdx.x * 256 + threadIdx.x) * 4;
  if (i >= n) return;
  float4 v = *(const float4*)(in + i);
  u16x4 o; o.x = f2bf(v.x); o.y = f2bf(v.y); o.z = f2bf(v.z); o.w = f2bf(v.w);
  *(u16x4*)(out + i) = o;
}

// per-row RMSNorm; block max -> partials[row] (NO global atomics)
__global__ __launch_bounds__(256) void rmsnorm_absmax_kernel(
    const float* __restrict__ xin, const float* __restrict__ wgt,
    u16* __restrict__ nxo, float* __restrict__ pmax)
{
  const int row = blockIdx.x, t = threadIdx.x;
  const int w = t >> 6, l = t & 63;
  float4 xv = *(const float4*)(xin + (size_t)row * DD + t * 4);
  float ss = xv.x*xv.x + xv.y*xv.y + xv.z*xv.z + xv.w*xv.w;
  #pragma unroll
  for (int m = 1; m < 64; m <<= 1) ss += __shfl_xor(ss, m, 64);
  __shared__ float red[4];
  __shared__ float redm[4];
  if (l == 0) red[w] = ss;
  __syncthreads();
  float tot = red[0] + red[1] + red[2] + red[3];
  float rstd = rsqrtf(tot * (1.f / DD) + 1e-6f);
  float4 wv = *(const float4*)(wgt + t * 4);
  float o0 = xv.x * rstd * wv.x;
  float o1 = xv.y * rstd * wv.y;
  float o2 = xv.z * rstd * wv.z;
  float o3 = xv.w * rstd * wv.w;
  u16x4 ov; ov.x = f2bf(o0); ov.y = f2bf(o1); ov.z = f2bf(o2); ov.w = f2bf(o3);
  *(u16x4*)(nxo + (size_t)row * DD + t * 4) = ov;
  float lm = fmaxf(fmaxf(fabsf(o0), fabsf(o1)), fmaxf(fabsf(o2), fabsf(o3)));
  #pragma unroll
  for (int m = 1; m < 64; m <<= 1) lm = fmaxf(lm, __shfl_xor(lm, m, 64));
  if (l == 0) redm[w] = lm;
  __syncthreads();
  if (t == 0)
    pmax[row] = fmaxf(fmaxf(redm[0], redm[1]), fmaxf(redm[2], redm[3]));
}

// single-block fold of partial maxima -> amax scalar
__global__ __launch_bounds__(1024) void amax_reduce_kernel(
    const float* __restrict__ p, int n, unsigned* __restrict__ amax)
{
  const int t = threadIdx.x;
  float m = 0.f;
  for (int i = t; i < n; i += 1024) m = fmaxf(m, p[i]);
  #pragma unroll
  for (int msk = 1; msk < 64; msk <<= 1) m = fmaxf(m, __shfl_xor(m, msk, 64));
  __shared__ float red[16];
  if ((t & 63) == 0) red[t >> 6] = m;
  __syncthreads();
  if (t == 0){
    float mm = red[0];
    #pragma unroll
    for (int i = 1; i < 16; i++) mm = fmaxf(mm, red[i]);
    *amax = __float_as_uint(mm);
  }
}

__global__ __launch_bounds__(256) void quantize_kernel(
    const u16* __restrict__ in, u16* __restrict__ outq,
    const unsigned* __restrict__ amax, int n)
{
  int i = (blockIdx.x * 256 + threadIdx.x) * 8;
  if (i >= n) return;
  float am = __uint_as_float(*amax);
  float scale = am / 127.f + 1e-8f;
  float inv = 1.f / scale;
  uint4 a = *(const uint4*)(in + i);
  u16* u = (u16*)&a;
  #pragma unroll
  for (int j = 0; j < 8; j++){
    float v = bf2f(u[j]);
    float q = rintf(v * inv);            // RNE = jnp.round
    q = fminf(127.f, fmaxf(-128.f, q));
    u[j] = f2bf(q * scale);
  }
  *(uint4*)(outq + i) = a;
}

// ---------------- GEMM: C[M,N] = A[M,K](bf16) @ W[N,K]^T + bias, fused epilogues ----------------
// MODE 0: bf16 store            (out=u16*)
// MODE 1: recurrence: tanh(C+b + exp(decay[col])*h_prev) -> f32  (e0=decay, e1=h_prev)
// MODE 2: mid-residual: x + h_rec + (C+b) + depthwise_conv(nx) -> f32
//         (e0=x, e1=h_rec, e2=conv_w, e3=conv_b, eb0=nx)
// MODE 4: out[idx] += (C+b)  (final residual)
template<int MODE>
__global__ __launch_bounds__(256) void gemm_bt(
    const u16* __restrict__ A, const u16* __restrict__ Wt,
    const float* __restrict__ bias, int M, int N, int K,
    void* __restrict__ out,
    const float* __restrict__ e0, const float* __restrict__ e1,
    const float* __restrict__ e2, const float* __restrict__ e3,
    const u16* __restrict__ eb0, float* __restrict__ pmax)
{
  __shared__ __align__(16) u16 Ash[128 * 32];
  __shared__ __align__(16) u16 Bsh[128 * 32];
  const int t = threadIdx.x, w = t >> 6, l = t & 63;
  const int brow = blockIdx.y * 128, bcol = blockIdx.x * 128;
  const int wr = w >> 1, wc = w & 1;
  f32x4 acc[4][4] = {};

  const u16* Ab = A + (size_t)brow * K;
  const u16* Bb = Wt + (size_t)bcol * K;
  const int r4 = t >> 2, c8 = (t & 3) * 8;

  for (int k0 = 0; k0 < K; k0 += 32){
    #pragma unroll
    for (int j = 0; j < 2; j++){
      async16(Ab + (size_t)(j * 64 + r4) * K + k0 + c8, &Ash[(j * 64 + r4) * 32 + c8]);
      async16(Bb + (size_t)(j * 64 + r4) * K + k0 + c8, &Bsh[(j * 64 + r4) * 32 + c8]);
    }
    __syncthreads();
    bf16x8 af[4], bfr[4];
    #pragma unroll
    for (int m = 0; m < 4; m++)
      af[m] = *(const bf16x8*)&Ash[(wr * 64 + m * 16 + (l & 15)) * 32 + (l >> 4) * 8];
    #pragma unroll
    for (int n = 0; n < 4; n++)
      bfr[n] = *(const bf16x8*)&Bsh[(wc * 64 + n * 16 + (l & 15)) * 32 + (l >> 4) * 8];
    #pragma unroll
    for (int m = 0; m < 4; m++)
      #pragma unroll
      for (int n = 0; n < 4; n++)
        acc[m][n] = __builtin_amdgcn_mfma_f32_16x16x32_bf16(af[m], bfr[n], acc[m][n], 0, 0, 0);
    __syncthreads();
  }

  #pragma unroll
  for (int m = 0; m < 4; m++){
    #pragma unroll
    for (int n = 0; n < 4; n++){
      #pragma unroll
      for (int r = 0; r < 4; r++){
        const int row = brow + wr * 64 + m * 16 + (l >> 4) * 4 + r;
        const int col = bcol + wc * 64 + n * 16 + (l & 15);
        const size_t idx = (size_t)row * N + col;
        float v = acc[m][n][r] + bias[col];
        if constexpr (MODE == 0){
          ((u16*)out)[idx] = f2bf(v);
        } else if constexpr (MODE == 1){
          v = tanhf(v + expf(e0[col]) * e1[idx]);
          ((float*)out)[idx] = v;
        } else if constexpr (MODE == 2){
          const int s = row & (SS - 1);
          float hc = e3[col];
          const u16* np = eb0 + idx;
          #pragma unroll
          for (int j = 0; j < 5; j++){
            int sn = s + j - 2;
            if (sn >= 0 && sn < SS) hc += bf2f(np[(j - 2) * DD]) * e2[col * 5 + j];
          }
          ((float*)out)[idx] = v + e0[idx] + e1[idx] + hc;
        } else {
          ((float*)out)[idx] += v;
        }
      }
    }
  }
  (void)pmax;
}

// ---------------- fused w1+w2 GEMM: g = silu(A@W1^T+b1) * (A@W2^T+b2) ----------------
// Same m97 sync structure as gemm_bt; two B tiles share one A staging.
// h1 never touches global memory. Block max -> pmax[block].
__global__ __launch_bounds__(256, 2) void gemm_dual_swiglu(
    const u16* __restrict__ A, const u16* __restrict__ W1t,
    const u16* __restrict__ W2t,
    const float* __restrict__ b1, const float* __restrict__ b2,
    int M, int N, int K,
    u16* __restrict__ out, float* __restrict__ pmax)
{
  __shared__ __align__(16) u16 Ash[128 * 32];
  __shared__ __align__(16) u16 B1sh[128 * 32];
  __shared__ __align__(16) u16 B2sh[128 * 32];
  const int t = threadIdx.x, w = t >> 6, l = t & 63;
  const int brow = blockIdx.y * 128, bcol = blockIdx.x * 128;
  const int wr = w >> 1, wc = w & 1;
  f32x4 acc1[4][4] = {};
  f32x4 acc2[4][4] = {};

  const u16* Ab  = A   + (size_t)brow * K;
  const u16* B1b = W1t + (size_t)bcol * K;
  const u16* B2b = W2t + (size_t)bcol * K;
  const int r4 = t >> 2, c8 = (t & 3) * 8;

  for (int k0 = 0; k0 < K; k0 += 32){
    #pragma unroll
    for (int j = 0; j < 2; j++){
      async16(Ab  + (size_t)(j * 64 + r4) * K + k0 + c8, &Ash [(j * 64 + r4) * 32 + c8]);
      async16(B1b + (size_t)(j * 64 + r4) * K + k0 + c8, &B1sh[(j * 64 + r4) * 32 + c8]);
      async16(B2b + (size_t)(j * 64 + r4) * K + k0 + c8, &B2sh[(j * 64 + r4) * 32 + c8]);
    }
    __syncthreads();
    bf16x8 af[4];
    #pragma unroll
    for (int m = 0; m < 4; m++)
      af[m] = *(const bf16x8*)&Ash[(wr * 64 + m * 16 + (l & 15)) * 32 + (l >> 4) * 8];
    #pragma unroll
    for (int n = 0; n < 4; n++){
      const int bo = (wc * 64 + n * 16 + (l & 15)) * 32 + (l >> 4) * 8;
      bf16x8 bf1 = *(const bf16x8*)&B1sh[bo];
      #pragma unroll
      for (int m = 0; m < 4; m++)
        acc1[m][n] = __builtin_amdgcn_mfma_f32_16x16x32_bf16(af[m], bf1, acc1[m][n], 0, 0, 0);
      bf16x8 bf2 = *(const bf16x8*)&B2sh[bo];
      #pragma unroll
      for (int m = 0; m < 4; m++)
        acc2[m][n] = __builtin_amdgcn_mfma_f32_16x16x32_bf16(af[m], bf2, acc2[m][n], 0, 0, 0);
    }
    __syncthreads();
  }

  float localmax = 0.f;
  #pragma unroll
  for (int m = 0; m < 4; m++){
    #pragma unroll
    for (int n = 0; n < 4; n++){
      #pragma unroll
      for (int r = 0; r < 4; r++){
        const int row = brow + wr * 64 + m * 16 + (l >> 4) * 4 + r;
        const int col = bcol + wc * 64 + n * 16 + (l & 15);
        const size_t idx = (size_t)row * N + col;
        float v1 = acc1[m][n][r] + b1[col];
        float v2 = acc2[m][n][r] + b2[col];
        float g = v1 / (1.f + expf(-v1)) * v2;    // silu(h1)*h2
        out[idx] = f2bf(g);
        localmax = fmaxf(localmax, fabsf(g));
      }
    }
  }
  #pragma unroll
  for (int msk = 1; msk < 64; msk <<= 1)
    localmax = fmaxf(localmax, __shfl_xor(localmax, msk, 64));
  __shared__ float wmax[4];
  if (l == 0) wmax[w] = localmax;
  __syncthreads();
  if (t == 0)
    pmax[blockIdx.y * gridDim.x + blockIdx.x] =
        fmaxf(fmaxf(wmax[0], wmax[1]), fmaxf(wmax[2], wmax[3]));
}

// ---------------- flash attention v4: v3 + XCD-aware block swizzle ----------------
__global__ __launch_bounds__(256) void attn_kernel(
    const u16* __restrict__ qkv, u16* __restrict__ attn_out)
{
  // bijective XCD swizzle (nwg=1024): each XCD owns 8 consecutive bh groups,
  // so all 16 q-blocks of a bh (plus 7 neighbors) share that XCD's L2 K/V.
  const int wg = blockIdx.y * gridDim.x + blockIdx.x;
  const int swz = (wg & 7) * 128 + (wg >> 3);
  const int qb = swz & 15;          // 16 q-blocks of 128 rows
  const int bh = swz >> 4;          // 0..63
  const int h = bh & (HH - 1), b = bh >> 4;
  const int t = threadIdx.x, w = t >> 6, l = t & 63;
  const int lm = l & 15, lh = l >> 4;
  const int tok0 = b * SS;
  const size_t rstr = 3 * DD;

  __shared__ __align__(16) u16 Ksh[64 * 64];       // [key][hd], row-XOR swizzle
  __shared__ __align__(16) u16 Vsh[64 * 64];       // [hd][key], vswz swizzle

  const int qr0 = qb * 128 + w * 32;
  bf16x8 qf[2][2];
  #pragma unroll
  for (int qt = 0; qt < 2; qt++){
    const u16* qp = qkv + (size_t)(tok0 + qr0 + qt * 16 + lm) * rstr + h * HDD + lh * 8;
    qf[qt][0] = *(const bf16x8*)qp;
    qf[qt][1] = *(const bf16x8*)(qp + 32);
  }
  f32x4 acc_o[2][4] = {};
  float mrun[2] = {-1e30f, -1e30f};
  float lrun[2] = {0.f, 0.f};

  for (int kv0 = 0; kv0 < SS; kv0 += 64){
    #pragma unroll
    for (int j = 0; j < 2; j++){
      const int krl = j * 32 + (t >> 3);
      const int c8 = (t & 7) * 8;
      const size_t rowb = (size_t)(tok0 + kv0 + krl) * rstr + h * HDD + c8;
      uint4 kv4 = *(const uint4*)(qkv + rowb + DD);
      *(uint4*)((char*)Ksh + (((krl * 64 + c8) * 2) ^ ((krl & 7) << 4))) = kv4;
      uint4 vv4 = *(const uint4*)(qkv + rowb + 2 * DD);
      const u16* vs = (const u16*)&vv4;
      #pragma unroll
      for (int i = 0; i < 8; i++){
        const int vr = c8 + i;
        *(u16*)((char*)Vsh + (((vr * 64 + krl) * 2) ^ vswz(vr))) = vs[i];
      }
    }
    __syncthreads();

    unsigned pk[2][4][2];
    #pragma unroll
    for (int qt = 0; qt < 2; qt++){
      f32x4 sc[4];
      #pragma unroll
      for (int n = 0; n < 4; n++){
        f32x4 z = {};
        #pragma unroll
        for (int kk = 0; kk < 2; kk++){
          const int krow = n * 16 + lm;
          bf16x8 kf = *(const bf16x8*)((const char*)Ksh +
              (((krow * 64 + kk * 32 + lh * 8) * 2) ^ ((krow & 7) << 4)));
          z = __builtin_amdgcn_mfma_f32_16x16x32_bf16(kf, qf[qt][kk], z, 0, 0, 0);
        }
        sc[n] = z;
      }
      float m0 = sc[0][0];
      #pragma unroll
      for (int n = 0; n < 4; n++)
        #pragma unroll
        for (int r = 0; r < 4; r++) m0 = fmaxf(m0, sc[n][r]);
      m0 = fmaxf(m0, __shfl_xor(m0, 16, 64));
      m0 = fmaxf(m0, __shfl_xor(m0, 32, 64));
      m0 *= 0.125f;
      float mn = fmaxf(mrun[qt], m0);
      float al = __expf(mrun[qt] - mn);
      mrun[qt] = mn;
      lrun[qt] *= al;
      #pragma unroll
      for (int r = 0; r < 4; r++){
        float alr = __shfl(al, lh * 4 + r, 64);
        #pragma unroll
        for (int n = 0; n < 4; n++) acc_o[qt][n][r] *= alr;
      }
      float rs = 0.f;
      #pragma unroll
      for (int n = 0; n < 4; n++)
        #pragma unroll
        for (int r = 0; r < 4; r++){
          float p = __expf(fmaf(sc[n][r], 0.125f, -mn));
          sc[n][r] = p;
          rs += p;
        }
      rs += __shfl_xor(rs, 16, 64);
      rs += __shfl_xor(rs, 32, 64);
      lrun[qt] += rs;
      #pragma unroll
      for (int n = 0; n < 4; n++){
        pk[qt][n][0] = cvtpk(sc[n][0], sc[n][1]);
        pk[qt][n][1] = cvtpk(sc[n][2], sc[n][3]);
      }
    }

    #pragma unroll
    for (int kk = 0; kk < 2; kk++){
      bf16x8 pA[2];
      #pragma unroll
      for (int qt = 0; qt < 2; qt++){
        union { bf16x8 v; unsigned u[4]; } pa;
        #pragma unroll
        for (int w4 = 0; w4 < 4; w4++){
          const int src = lm + 16 * (2 * (lh & 1) + (w4 >> 1));
          unsigned a0 = (unsigned)__shfl((int)pk[qt][2 * kk + 0][w4 & 1], src, 64);
          unsigned a1 = (unsigned)__shfl((int)pk[qt][2 * kk + 1][w4 & 1], src, 64);
          pa.u[w4] = (lh >> 1) ? a1 : a0;
        }
        pA[qt] = pa.v;
      }
      #pragma unroll
      for (int n = 0; n < 4; n++){
        const int vr = n * 16 + lm;
        bf16x8 vf = *(const bf16x8*)((const char*)Vsh +
            (((vr * 64 + kk * 32 + lh * 8) * 2) ^ vswz(vr)));
        acc_o[0][n] = __builtin_amdgcn_mfma_f32_16x16x32_bf16(pA[0], vf, acc_o[0][n], 0, 0, 0);
        acc_o[1][n] = __builtin_amdgcn_mfma_f32_16x16x32_bf16(pA[1], vf, acc_o[1][n], 0, 0, 0);
      }
    }
    __syncthreads();
  }

  #pragma unroll
  for (int qt = 0; qt < 2; qt++){
    const float inv = 1.f / lrun[qt];
    #pragma unroll
    for (int r = 0; r < 4; r++){
      const float invr = __shfl(inv, lh * 4 + r, 64);
      const int row = tok0 + qr0 + qt * 16 + lh * 4 + r;
      #pragma unroll
      for (int n = 0; n < 4; n++)
        attn_out[(size_t)row * DD + h * HDD + n * 16 + lm] = f2bf(acc_o[qt][n][r] * invr);
    }
  }
}

// ---------------- host ----------------

extern "C" void kernel_launch(void* const* d_in, const int* in_sizes, int n_in,
                              void* d_out, int out_size, void* d_ws, size_t ws_size,
                              hipStream_t stream)
{
  (void)in_sizes; (void)n_in; (void)out_size; (void)ws_size;
  const float* x       = (const float*)d_in[0];
  const float* h_prev  = (const float*)d_in[1];
  const float* norm1_w = (const float*)d_in[2];
  const float* norm2_w = (const float*)d_in[3];
  const float* decay   = (const float*)d_in[4];
  const float* rec_W   = (const float*)d_in[5];
  const float* rec_b   = (const float*)d_in[6];
  const float* inp_W   = (const float*)d_in[7];
  const float* inp_b   = (const float*)d_in[8];
  const float* out_W   = (const float*)d_in[9];
  const float* out_b   = (const float*)d_in[10];
  const float* conv_w  = (const float*)d_in[11];
  const float* conv_b  = (const float*)d_in[12];
  const float* w1_W    = (const float*)d_in[13];
  const float* w1_b    = (const float*)d_in[14];
  const float* w2_W    = (const float*)d_in[15];
  const float* w2_b    = (const float*)d_in[16];
  const float* w3_W    = (const float*)d_in[17];
  const float* w3_b    = (const float*)d_in[18];

  const size_t NDe = (size_t)NTOK * DD;
  float* out_x = (float*)d_out;
  float* out_h = (float*)d_out + NDe;

  char* ws = (char*)d_ws;
  unsigned* amax1 = (unsigned*)ws;
  unsigned* amax2 = amax1 + 1;
  unsigned* amax3 = amax1 + 2;
  size_t off = 256;
  u16* Wrec = (u16*)(ws + off); off += (size_t)DD * DD * 2;
  u16* Winp = (u16*)(ws + off); off += (size_t)3 * DD * DD * 2;
  u16* Wout = (u16*)(ws + off); off += (size_t)DD * DD * 2;
  u16* W1   = (u16*)(ws + off); off += (size_t)4 * DD * DD * 2;
  u16* W2   = (u16*)(ws + off); off += (size_t)4 * DD * DD * 2;
  u16* W3   = (u16*)(ws + off); off += (size_t)4 * DD * DD * 2;
  u16* nx   = (u16*)(ws + off); off += NDe * 2;
  u16* xq   = (u16*)(ws + off); off += NDe * 2;
  u16* big  = (u16*)(ws + off); off += (size_t)NTOK * 4096 * 2;  // qkv+attn_out OR g
  float* pmax1 = (float*)(ws + off); off += NTOK * 4;
  float* pmax2 = (float*)(ws + off); off += NTOK * 4;
  float* pmax3 = (float*)(ws + off); off += 2048 * 4;
  u16* qkvp    = big;
  u16* attnout = big + (size_t)NTOK * 3 * DD;

  // weights -> bf16
  f32_to_bf16_kernel<<<dim3(1024),  dim3(256), 0, stream>>>(rec_W, Wrec, DD * DD);
  f32_to_bf16_kernel<<<dim3(3072),  dim3(256), 0, stream>>>(inp_W, Winp, 3 * DD * DD);
  f32_to_bf16_kernel<<<dim3(1024),  dim3(256), 0, stream>>>(out_W, Wout, DD * DD);
  f32_to_bf16_kernel<<<dim3(4096),  dim3(256), 0, stream>>>(w1_W, W1, 4 * DD * DD);
  f32_to_bf16_kernel<<<dim3(4096),  dim3(256), 0, stream>>>(w2_W, W2, 4 * DD * DD);
  f32_to_bf16_kernel<<<dim3(4096),  dim3(256), 0, stream>>>(w3_W, W3, 4 * DD * DD);

  // phase 1: norm + absmax (two-stage), quantize
  rmsnorm_absmax_kernel<<<dim3(NTOK), dim3(256), 0, stream>>>(x, norm1_w, nx, pmax1);
  amax_reduce_kernel<<<dim3(1), dim3(1024), 0, stream>>>(pmax1, NTOK, amax1);
  quantize_kernel<<<dim3(4096), dim3(256), 0, stream>>>(nx, xq, amax1, (int)NDe);

  // recurrence branch: h_rec -> out_h
  gemm_bt<1><<<dim3(8, 64), dim3(256), 0, stream>>>(xq, Wrec, rec_b, NTOK, DD, DD,
      out_h, decay, h_prev, nullptr, nullptr, nullptr, nullptr);
  // attention branch
  gemm_bt<0><<<dim3(24, 64), dim3(256), 0, stream>>>(nx, Winp, inp_b, NTOK, 3 * DD, DD,
      qkvp, nullptr, nullptr, nullptr, nullptr, nullptr, nullptr);
  attn_kernel<<<dim3(16, 64), dim3(256), 0, stream>>>(qkvp, attnout);
  // out-proj + residual + conv -> out_x (= x_mid)
  gemm_bt<2><<<dim3(8, 64), dim3(256), 0, stream>>>(attnout, Wout, out_b, NTOK, DD, DD,
      out_x, x, out_h, conv_w, conv_b, nx, nullptr);

  // phase 2: FFN
  rmsnorm_absmax_kernel<<<dim3(NTOK), dim3(256), 0, stream>>>(out_x, norm2_w, nx, pmax2);
  amax_reduce_kernel<<<dim3(1), dim3(1024), 0, stream>>>(pmax2, NTOK, amax2);
  quantize_kernel<<<dim3(4096), dim3(256), 0, stream>>>(nx, xq, amax2, (int)NDe);
  // fused w1+w2+swiglu gate -> g (bf16) + block maxima
  gemm_dual_swiglu<<<dim3(32, 64), dim3(256), 0, stream>>>(xq, W1, W2, w1_b, w2_b,
      NTOK, 4 * DD, DD, big, pmax3);
  amax_reduce_kernel<<<dim3(1), dim3(1024), 0, stream>>>(pmax3, 2048, amax3);
  quantize_kernel<<<dim3(16384), dim3(256), 0, stream>>>(big, big, amax3, NTOK * 4096);
  gemm_bt<4><<<dim3(8, 64), dim3(256), 0, stream>>>(big, W3, w3_b, NTOK, DD, 4 * DD,
      out_x, nullptr, nullptr, nullptr, nullptr, nullptr, nullptr);
}